// Round 4
// baseline (14410.310 us; speedup 1.0000x reference)
//
#include <hip/hip_runtime.h>
#include <hip/hip_bf16.h>

// RNNColorbot round 4: single persistent kernel, per-rowgroup flag pipeline
// (no per-step launches), register-resident cell state across all 128 steps,
// B/chars prefetch hidden under the dependency spin. Keeps round-3's BK=128
// swizzled-LDS + global_load_lds x16 + register-resident gate update.

typedef __hip_bfloat16 bf16;
typedef __attribute__((ext_vector_type(8))) short bfrag8;   // 8 bf16 = 4 VGPRs
typedef __attribute__((ext_vector_type(4))) float accf4;    // MFMA accum

#define BATCH 512
#define TSTEPS 128
#define DIN 256
#define H 1024
#define NG 4096   // 4*H gate columns

__device__ __forceinline__ float sigm(float x) { return 1.0f / (1.0f + __expf(-x)); }
__device__ __forceinline__ float tanh_f(float x) {
    float a = fabsf(x);
    float e = __expf(-2.0f * a);
    float t = (1.0f - e) / (1.0f + e);
    return x < 0.0f ? -t : t;
}
__device__ __forceinline__ unsigned short bfr16(float x) {
    bf16 h = __float2bfloat16(x);
    return *(unsigned short*)&h;
}
// async global->LDS, 16B/lane. HW dest = wave-uniform LDS base + lane*16.
__device__ __forceinline__ void gll16(const void* g, void* l) {
    __builtin_amdgcn_global_load_lds(
        (const __attribute__((address_space(1))) unsigned int*)g,
        (__attribute__((address_space(3))) unsigned int*)l, 16, 0, 0);
}

// ---------------------------------------------------------------------------
// Repack [W;U] (fp32, K x 4096) -> Bp bf16 [KT][4096][128], gate-16 permuted:
//   new col n -> orig ((n>>4)&3)*1024 + (n>>7)*32 + ((n>>6)&1)*16 + (n&15)
// (each 64-col wave tile = gates [i|f|g|o] x 16 h-cols), XOR-swizzled in 16B
// chunks: chunk kc of row n stored at position kc ^ (n&7), so global layout
// == LDS layout and global_load_lds copies linearly.
// ---------------------------------------------------------------------------
__global__ void k_repack(const float* __restrict__ W, const float* __restrict__ U,
                         bf16* __restrict__ Bp, int KIN)
{
    __shared__ float tile[128][65];
    int kt = blockIdx.x, nt = blockIdx.y;
    int lane = threadIdx.x;     // 64 threads
    int n = nt * 64 + lane;
    int orig = ((n >> 4) & 3) * 1024 + (n >> 7) * 32 + ((n >> 6) & 1) * 16 + (n & 15);
    for (int j = 0; j < 128; ++j) {
        int k = kt * 128 + j;
        tile[j][lane] = (k < KIN) ? W[(size_t)k * NG + orig]
                                  : U[(size_t)(k - KIN) * NG + orig];
    }
    __syncthreads();
    for (int u = 0; u < 16; ++u) {
        int cid = u * 64 + lane;           // 1024 chunks
        int nloc = cid >> 4;
        int pos = cid & 15;
        int nn = nt * 64 + nloc;
        int kc = pos ^ (nn & 7);           // logical chunk stored here
        alignas(16) unsigned short pk[8];
        #pragma unroll
        for (int jj = 0; jj < 8; ++jj) pk[jj] = bfr16(tile[kc * 8 + jj][nloc]);
        *(int4*)(Bp + ((size_t)kt * NG + nn) * 128 + pos * 8) = *(int4*)pk;
    }
}

// ---------------------------------------------------------------------------
// Persistent fused 2-layer LSTM. 512 blocks (2/CU): bid<256 -> L1 job,
// bid>=256 -> L2 job; each block owns (ntile, rowgroup) for all 128 steps.
// Per-rowgroup monotonic counters (32 ntile-blocks each) gate the pipeline:
//   L1(t): cnt1[rg] >= 32t      && cnt2[rg] >= 32(t-1)   (WAR on h1 pingpong)
//   L2(t): cnt1[rg] >= 32(t+1)  && cnt2[rg] >= 32t
// Cell state stays in registers across all t (8 floats/thread).
// ---------------------------------------------------------------------------
struct PP {
    const float* chars; const int* seqlen;
    const bf16* Bp1; const bf16* Bp2;
    const float* b1; const float* b2;
    bf16* h1; bf16* h2; float* hidden;
    int* cnt1; int* cnt2;     // [8] rowgroup counters, 64B-strided
};

__global__ __launch_bounds__(256, 2) void k_persist(PP P)
{
    __shared__ __align__(16) bf16 Alds[64 * 128];    // 16 KB, swizzled
    __shared__ __align__(16) bf16 Blds[128 * 128];   // 32 KB, swizzled

    const int bid = blockIdx.x;
    const int job = bid >> 8;            // 0: layer1, 1: layer2
    const int bi = bid & 255;
    const int tid = threadIdx.x;
    const int wv = tid >> 6, lane = tid & 63;
    const int ntile = bi & 31, rg = bi >> 5;
    const int b0 = rg * 64, n0 = ntile * 128;
    const int mw = (wv & 1) * 32, nw = (wv >> 1) * 64;
    const int c = lane & 15, q = lane >> 4;

    const bf16* Bp = job ? P.Bp2 : P.Bp1;
    const float* bias = job ? P.b2 : P.b1;
    const int KT = job ? 16 : 10;
    const int ksplit = job ? 1024 : 256;
    const size_t HS = (size_t)BATCH * H;

    // ---- fixed epilogue coordinates (hoisted out of the t-loop) ----
    const int hcol = ntile * 32 + (wv >> 1) * 16 + c;
    const float bi_ = bias[hcol],         bf_ = bias[H + hcol];
    const float bg_ = bias[2 * H + hcol], bo_ = bias[3 * H + hcol];
    const int seg = hcol & ~127;
    const int kc_ = (hcol & 127) >> 3;
    const int jl = hcol & 7;
    int houti[8]; int hidi[8]; int sl[8]; float cellv[8];
    #pragma unroll
    for (int u = 0; u < 8; ++u) {
        int b = b0 + mw + (u >> 2) * 16 + q * 4 + (u & 3);
        houti[u] = b * H + seg + (((kc_ ^ (b & 7))) << 3) + jl;
        hidi[u] = b * H + hcol;
        sl[u] = job ? (P.seqlen[b] - 1) : -1;
        cellv[u] = 0.f;
    }

    int* cme = (job ? P.cnt2 : P.cnt1) + rg * 16;
    int* cn1 = P.cnt1 + rg * 16;
    int* cn2 = P.cnt2 + rg * 16;

    auto stageChars = [&](int t_, int k0) {
        #pragma unroll
        for (int uu = 0; uu < 4; ++uu) {
            int u = uu * 256 + tid;            // chunk id 0..1023
            int r = u >> 4;                    // row
            int pos = u & 15;                  // swizzled position
            int kc = pos ^ (r & 7);            // logical k-chunk
            const float* src = P.chars + (size_t)(b0 + r) * (TSTEPS * DIN)
                             + (size_t)t_ * DIN + k0 + kc * 8;
            float4 va = *(const float4*)src;
            float4 vb = *(const float4*)(src + 4);
            alignas(16) unsigned short pk[8];
            pk[0] = bfr16(va.x); pk[1] = bfr16(va.y);
            pk[2] = bfr16(va.z); pk[3] = bfr16(va.w);
            pk[4] = bfr16(vb.x); pk[5] = bfr16(vb.y);
            pk[6] = bfr16(vb.z); pk[7] = bfr16(vb.w);
            *(int4*)((char*)Alds + u * 16) = *(int4*)pk;
        }
    };
    auto stageH = [&](const bf16* Asrc, int kk0) {
        #pragma unroll
        for (int cc = 0; cc < 4; ++cc) {
            int ob = wv * 4096 + cc * 1024;
            int o = ob + lane * 16;
            int r = o >> 8;
            const char* g = (const char*)Asrc + (size_t)(b0 + r) * (H * 2)
                          + kk0 * 2 + (o & 255);
            gll16(g, (char*)Alds + ob);
        }
    };
    auto stageB = [&](int kt) {
        const char* Bg = (const char*)Bp + ((size_t)kt * NG + n0) * 256;
        #pragma unroll
        for (int cc = 0; cc < 8; ++cc) {
            int ob = wv * 8192 + cc * 1024;
            gll16(Bg + ob + lane * 16, (char*)Blds + ob);
        }
    };

    for (int t = 0; t < TSTEPS; ++t) {
        const bf16* A0 = job ? (P.h1 + (size_t)(t & 1) * HS) : nullptr;
        const bf16* A1 = (job ? P.h2 : P.h1) + (size_t)((t + 1) & 1) * HS;
        bf16* Hout = (job ? P.h2 : P.h1) + (size_t)(t & 1) * HS;

        // ---- dependency-free prefetch (hidden under the spin) ----
        stageB(0);
        if (!job) stageChars(t, 0);          // L1 kt=0 A-tile is chars

        // ---- spin on pipeline flags ----
        int n1 = job ? 32 * (t + 1) : 32 * t;
        int n2 = job ? 32 * t       : 32 * (t - 1);
        if (tid == 0) {
            while (__hip_atomic_load(cn1, __ATOMIC_RELAXED, __HIP_MEMORY_SCOPE_AGENT) < n1 ||
                   __hip_atomic_load(cn2, __ATOMIC_RELAXED, __HIP_MEMORY_SCOPE_AGENT) < n2)
                __builtin_amdgcn_s_sleep(8);
        }
        __syncthreads();
        __threadfence();                     // acquire: inv L1 before reading h
        if (job) stageH(A0, 0);              // L2 kt=0 A-tile = h1(t)

        accf4 acc[2][4];
        #pragma unroll
        for (int i = 0; i < 2; ++i)
            #pragma unroll
            for (int jz = 0; jz < 4; ++jz) acc[i][jz] = accf4{0.f, 0.f, 0.f, 0.f};

        for (int kt = 0; kt < KT; ++kt) {
            if (kt > 0) {
                int k0 = kt << 7;
                if (!job && k0 < ksplit) stageChars(t, k0);
                else if (k0 < ksplit)    stageH(A0, k0);
                else                     stageH(A1, k0 - ksplit);
                stageB(kt);
            }
            __syncthreads();     // compiler drains vmcnt before barrier
            #pragma unroll
            for (int kk = 0; kk < 128; kk += 32) {
                int kc = (kk >> 3) + q;                  // logical chunk
                int ra = mw + c;
                int pa = (kc ^ (ra & 7)) << 3;           // (ra+16)&7 == ra&7
                bfrag8 af0 = *(const bfrag8*)(Alds + ra * 128 + pa);
                bfrag8 af1 = *(const bfrag8*)(Alds + (ra + 16) * 128 + pa);
                #pragma unroll
                for (int nt = 0; nt < 4; ++nt) {
                    int nn = nw + nt * 16 + c;
                    bfrag8 bfv = *(const bfrag8*)(Blds + nn * 128 + ((kc ^ (nn & 7)) << 3));
                    acc[0][nt] = __builtin_amdgcn_mfma_f32_16x16x32_bf16(af0, bfv, acc[0][nt], 0, 0, 0);
                    acc[1][nt] = __builtin_amdgcn_mfma_f32_16x16x32_bf16(af1, bfv, acc[1][nt], 0, 0, 0);
                }
            }
            __syncthreads();
        }

        // ---- register-resident cell update ----
        #pragma unroll
        for (int u = 0; u < 8; ++u) {
            int mt = u >> 2, reg = u & 3;
            float ig = sigm(acc[mt][0][reg] + bi_);
            float fg = sigm(acc[mt][1][reg] + bf_);
            float gv = tanh_f(acc[mt][2][reg] + bg_);
            float og = sigm(acc[mt][3][reg] + bo_);
            float cv = fg * cellv[u] + ig * gv;
            cellv[u] = cv;
            float h = og * tanh_f(cv);
            Hout[houti[u]] = __float2bfloat16(h);     // swizzled store
            if (job && sl[u] == t) P.hidden[hidi[u]] = h;
        }

        // ---- publish: stores drained, then release-increment ----
        __threadfence();
        __syncthreads();
        if (tid == 0)
            __hip_atomic_fetch_add(cme, 1, __ATOMIC_RELEASE, __HIP_MEMORY_SCOPE_AGENT);
    }
}

// ---------------------------------------------------------------------------
// out[b][l] = relu(hidden[b]·Wd[:,l] + bd[l]), 512 blocks x 1 wave
// ---------------------------------------------------------------------------
__global__ void k_final(const float* __restrict__ hidden, const float* __restrict__ Wd,
                        const float* __restrict__ bd, float* __restrict__ out)
{
    int b = blockIdx.x;
    int l = threadIdx.x;
    float p0 = 0.f, p1 = 0.f, p2 = 0.f;
    for (int jj = l; jj < H; jj += 64) {
        float hv = hidden[(size_t)b * H + jj];
        p0 += hv * Wd[jj * 3 + 0];
        p1 += hv * Wd[jj * 3 + 1];
        p2 += hv * Wd[jj * 3 + 2];
    }
    #pragma unroll
    for (int off = 32; off > 0; off >>= 1) {
        p0 += __shfl_down(p0, off);
        p1 += __shfl_down(p1, off);
        p2 += __shfl_down(p2, off);
    }
    if (l == 0) {
        out[b * 3 + 0] = fmaxf(p0 + bd[0], 0.f);
        out[b * 3 + 1] = fmaxf(p1 + bd[1], 0.f);
        out[b * 3 + 2] = fmaxf(p2 + bd[2], 0.f);
    }
}

extern "C" void kernel_launch(void* const* d_in, const int* in_sizes, int n_in,
                              void* d_out, int out_size, void* d_ws, size_t ws_size,
                              hipStream_t stream)
{
    const float* chars = (const float*)d_in[0];
    const int* seqlen  = (const int*)d_in[1];
    const float* W1 = (const float*)d_in[2];
    const float* U1 = (const float*)d_in[3];
    const float* b1 = (const float*)d_in[4];
    const float* W2 = (const float*)d_in[5];
    const float* U2 = (const float*)d_in[6];
    const float* b2 = (const float*)d_in[7];
    const float* Wd = (const float*)d_in[8];
    const float* bd = (const float*)d_in[9];
    float* out = (float*)d_out;

    char* ws = (char*)d_ws;
    size_t off = 0;
    bf16* Bp1 = (bf16*)(ws + off); off += (size_t)10 * NG * 128 * 2;  // 10.0 MB
    bf16* Bp2 = (bf16*)(ws + off); off += (size_t)16 * NG * 128 * 2;  // 16.0 MB
    bf16* h1  = (bf16*)(ws + off); off += (size_t)2 * BATCH * H * 2;  // 2 MB ping-pong
    bf16* h2  = (bf16*)(ws + off); off += (size_t)2 * BATCH * H * 2;  // 2 MB
    float* hidden = (float*)(ws + off); off += (size_t)BATCH * H * 4; // 2 MB
    int* cnt1 = (int*)(ws + off); off += 8 * 16 * 4;                  // 512 B
    int* cnt2 = (int*)(ws + off); off += 8 * 16 * 4;                  // 512 B
    if (ws_size < off) return;  // ~32 MB needed

    hipMemsetAsync(h1, 0, (size_t)2 * BATCH * H * 2, stream);
    hipMemsetAsync(h2, 0, (size_t)2 * BATCH * H * 2, stream);
    hipMemsetAsync(cnt1, 0, 2 * 8 * 16 * 4, stream);

    k_repack<<<dim3(10, 64), 64, 0, stream>>>(W1, U1, Bp1, 256);
    k_repack<<<dim3(16, 64), 64, 0, stream>>>(W2, U2, Bp2, 1024);

    PP P;
    P.chars = chars; P.seqlen = seqlen;
    P.Bp1 = Bp1; P.Bp2 = Bp2; P.b1 = b1; P.b2 = b2;
    P.h1 = h1; P.h2 = h2; P.hidden = hidden;
    P.cnt1 = cnt1; P.cnt2 = cnt2;

    k_persist<<<512, 256, 0, stream>>>(P);
    k_final<<<512, 64, 0, stream>>>(hidden, Wd, bd, out);
}

// Round 5
// 3687.487 us; speedup vs baseline: 3.9079x; 3.9079x over previous
//
#include <hip/hip_runtime.h>
#include <hip/hip_bf16.h>

// RNNColorbot round 5: persistent flag-pipelined 2-layer LSTM, NO cache-wide
// fences. h1/h2 exchange is made coherent per-access (sc1 write-through
// stores + sc1 forced-miss global_load_lds); weights/chars stay hot in the
// per-XCD L2. Round 4's threadfence (buffer_inv) was re-fetching all 26 MB
// of weights every step (FETCH_SIZE 3 GB) — this round removes it.

typedef __hip_bfloat16 bf16;
typedef __attribute__((ext_vector_type(8))) short bfrag8;   // 8 bf16 = 4 VGPRs
typedef __attribute__((ext_vector_type(4))) float accf4;    // MFMA accum

#define BATCH 512
#define TSTEPS 128
#define DIN 256
#define H 1024
#define NG 4096   // 4*H gate columns

__device__ __forceinline__ float sigm(float x) { return 1.0f / (1.0f + __expf(-x)); }
__device__ __forceinline__ float tanh_f(float x) {
    float a = fabsf(x);
    float e = __expf(-2.0f * a);
    float t = (1.0f - e) / (1.0f + e);
    return x < 0.0f ? -t : t;
}
__device__ __forceinline__ unsigned short bfr16(float x) {
    bf16 h = __float2bfloat16(x);
    return *(unsigned short*)&h;
}
// async global->LDS, 16B/lane, normal caching (read-only data: B, chars)
__device__ __forceinline__ void gll16(const void* g, void* l) {
    __builtin_amdgcn_global_load_lds(
        (const __attribute__((address_space(1))) unsigned int*)g,
        (__attribute__((address_space(3))) unsigned int*)l, 16, 0, 0);
}
// coherent variant for cross-XCD h exchange: aux=16 -> sc1 (device scope,
// forced miss past the local L2 which may hold a stale ping-pong line)
__device__ __forceinline__ void gll16c(const void* g, void* l) {
    __builtin_amdgcn_global_load_lds(
        (const __attribute__((address_space(1))) unsigned int*)g,
        (__attribute__((address_space(3))) unsigned int*)l, 16, 0, 16);
}
// write-through device-coherent 2B store (h exchange; leaves L2 clean)
__device__ __forceinline__ void store_short_coh(void* p, unsigned short v) {
    unsigned int vv = v;
    asm volatile("global_store_short %0, %1, off sc0 sc1"
                 :: "v"(p), "v"(vv) : "memory");
}

// ---------------------------------------------------------------------------
// Repack [W;U] (fp32, K x 4096) -> Bp bf16 [KT][4096][128], gate-16 permuted:
//   new col n -> orig ((n>>4)&3)*1024 + (n>>7)*32 + ((n>>6)&1)*16 + (n&15)
// (each 64-col wave tile = gates [i|f|g|o] x 16 h-cols), XOR-swizzled in 16B
// chunks: chunk kc of row n stored at position kc ^ (n&7), so global layout
// == LDS layout and global_load_lds copies linearly.
// ---------------------------------------------------------------------------
__global__ void k_repack(const float* __restrict__ W, const float* __restrict__ U,
                         bf16* __restrict__ Bp, int KIN)
{
    __shared__ float tile[128][65];
    int kt = blockIdx.x, nt = blockIdx.y;
    int lane = threadIdx.x;     // 64 threads
    int n = nt * 64 + lane;
    int orig = ((n >> 4) & 3) * 1024 + (n >> 7) * 32 + ((n >> 6) & 1) * 16 + (n & 15);
    for (int j = 0; j < 128; ++j) {
        int k = kt * 128 + j;
        tile[j][lane] = (k < KIN) ? W[(size_t)k * NG + orig]
                                  : U[(size_t)(k - KIN) * NG + orig];
    }
    __syncthreads();
    for (int u = 0; u < 16; ++u) {
        int cid = u * 64 + lane;           // 1024 chunks
        int nloc = cid >> 4;
        int pos = cid & 15;
        int nn = nt * 64 + nloc;
        int kc = pos ^ (nn & 7);           // logical chunk stored here
        alignas(16) unsigned short pk[8];
        #pragma unroll
        for (int jj = 0; jj < 8; ++jj) pk[jj] = bfr16(tile[kc * 8 + jj][nloc]);
        *(int4*)(Bp + ((size_t)kt * NG + nn) * 128 + pos * 8) = *(int4*)pk;
    }
}

// ---------------------------------------------------------------------------
// Persistent fused 2-layer LSTM. 512 blocks (2/CU): bid<256 -> L1, else L2;
// each block owns (ntile, rowgroup) for all 128 steps. Per-rowgroup monotonic
// counters gate the pipeline:
//   L1(t): cnt1 >= 32t      && cnt2 >= 32(t-1)   (WAR on h1 pingpong)
//   L2(t): cnt1 >= 32(t+1)  && cnt2 >= 32t
// Cell state lives in registers across all t. blockIdx%8 == ntile%8 -> all 8
// rowgroups of an ntile share one XCD (weights stay in that L2).
// ---------------------------------------------------------------------------
struct PP {
    const float* chars; const int* seqlen;
    const bf16* Bp1; const bf16* Bp2;
    const float* b1; const float* b2;
    bf16* h1; bf16* h2; float* hidden;
    int* cnt1; int* cnt2;     // [8] rowgroup counters, 64B-strided
};

__global__ __launch_bounds__(256, 2) void k_persist(PP P)
{
    __shared__ __align__(16) bf16 Alds[64 * 128];    // 16 KB, swizzled
    __shared__ __align__(16) bf16 Blds[128 * 128];   // 32 KB, swizzled

    const int bid = blockIdx.x;
    const int job = bid >> 8;            // 0: layer1, 1: layer2
    const int bi = bid & 255;
    const int tid = threadIdx.x;
    const int wv = tid >> 6, lane = tid & 63;
    const int ntile = bi & 31, rg = bi >> 5;
    const int b0 = rg * 64, n0 = ntile * 128;
    const int mw = (wv & 1) * 32, nw = (wv >> 1) * 64;
    const int c = lane & 15, q = lane >> 4;

    const bf16* Bp = job ? P.Bp2 : P.Bp1;
    const float* bias = job ? P.b2 : P.b1;
    const int KT = job ? 16 : 10;
    const int ksplit = job ? 1024 : 256;
    const size_t HS = (size_t)BATCH * H;

    // ---- fixed epilogue coordinates (hoisted out of the t-loop) ----
    const int hcol = ntile * 32 + (wv >> 1) * 16 + c;
    const float bi_ = bias[hcol],         bf_ = bias[H + hcol];
    const float bg_ = bias[2 * H + hcol], bo_ = bias[3 * H + hcol];
    const int seg = hcol & ~127;
    const int kc_ = (hcol & 127) >> 3;
    const int jl = hcol & 7;
    int houti[8]; int hidi[8]; int sl[8]; float cellv[8];
    #pragma unroll
    for (int u = 0; u < 8; ++u) {
        int b = b0 + mw + (u >> 2) * 16 + q * 4 + (u & 3);
        houti[u] = b * H + seg + (((kc_ ^ (b & 7))) << 3) + jl;
        hidi[u] = b * H + hcol;
        sl[u] = job ? (P.seqlen[b] - 1) : -1;
        cellv[u] = 0.f;
    }

    int* cme = (job ? P.cnt2 : P.cnt1) + rg * 16;
    int* cn1 = P.cnt1 + rg * 16;
    int* cn2 = P.cnt2 + rg * 16;

    auto stageChars = [&](int t_, int k0) {
        #pragma unroll
        for (int uu = 0; uu < 4; ++uu) {
            int u = uu * 256 + tid;            // chunk id 0..1023
            int r = u >> 4;                    // row
            int pos = u & 15;                  // swizzled position
            int kc = pos ^ (r & 7);            // logical k-chunk
            const float* src = P.chars + (size_t)(b0 + r) * (TSTEPS * DIN)
                             + (size_t)t_ * DIN + k0 + kc * 8;
            float4 va = *(const float4*)src;
            float4 vb = *(const float4*)(src + 4);
            alignas(16) unsigned short pk[8];
            pk[0] = bfr16(va.x); pk[1] = bfr16(va.y);
            pk[2] = bfr16(va.z); pk[3] = bfr16(va.w);
            pk[4] = bfr16(vb.x); pk[5] = bfr16(vb.y);
            pk[6] = bfr16(vb.z); pk[7] = bfr16(vb.w);
            *(int4*)((char*)Alds + u * 16) = *(int4*)pk;
        }
    };
    auto stageH = [&](const bf16* Asrc, int kk0) {
        #pragma unroll
        for (int cc = 0; cc < 4; ++cc) {
            int ob = wv * 4096 + cc * 1024;
            int o = ob + lane * 16;
            int r = o >> 8;
            const char* g = (const char*)Asrc + (size_t)(b0 + r) * (H * 2)
                          + kk0 * 2 + (o & 255);
            gll16c(g, (char*)Alds + ob);       // sc1: forced-miss coherent
        }
    };
    auto stageB = [&](int kt) {
        const char* Bg = (const char*)Bp + ((size_t)kt * NG + n0) * 256;
        #pragma unroll
        for (int cc = 0; cc < 8; ++cc) {
            int ob = wv * 8192 + cc * 1024;
            gll16(Bg + ob + lane * 16, (char*)Blds + ob);   // L2-cached
        }
    };

    for (int t = 0; t < TSTEPS; ++t) {
        const bf16* A0 = job ? (P.h1 + (size_t)(t & 1) * HS) : nullptr;
        const bf16* A1 = (job ? P.h2 : P.h1) + (size_t)((t + 1) & 1) * HS;
        bf16* Hout = (job ? P.h2 : P.h1) + (size_t)(t & 1) * HS;

        // ---- dependency-free prefetch (hidden under the spin) ----
        stageB(0);
        if (!job) stageChars(t, 0);          // L1 kt=0 A-tile is chars

        // ---- spin on pipeline flags (relaxed; atomics are coherent) ----
        int n1 = job ? 32 * (t + 1) : 32 * t;
        int n2 = job ? 32 * t       : 32 * (t - 1);
        if (tid == 0) {
            while (__hip_atomic_load(cn1, __ATOMIC_RELAXED, __HIP_MEMORY_SCOPE_AGENT) < n1 ||
                   __hip_atomic_load(cn2, __ATOMIC_RELAXED, __HIP_MEMORY_SCOPE_AGENT) < n2)
                __builtin_amdgcn_s_sleep(8);
        }
        __syncthreads();                     // NO fence: h loads are sc1
        if (job) stageH(A0, 0);              // L2 kt=0 A-tile = h1(t)

        accf4 acc[2][4];
        #pragma unroll
        for (int i = 0; i < 2; ++i)
            #pragma unroll
            for (int jz = 0; jz < 4; ++jz) acc[i][jz] = accf4{0.f, 0.f, 0.f, 0.f};

        for (int kt = 0; kt < KT; ++kt) {
            if (kt > 0) {
                int k0 = kt << 7;
                if (!job && k0 < ksplit) stageChars(t, k0);
                else if (k0 < ksplit)    stageH(A0, k0);
                else                     stageH(A1, k0 - ksplit);
                stageB(kt);
            }
            __syncthreads();     // compiler drains vmcnt before barrier
            #pragma unroll
            for (int kk = 0; kk < 128; kk += 32) {
                int kc = (kk >> 3) + q;                  // logical chunk
                int ra = mw + c;
                int pa = (kc ^ (ra & 7)) << 3;           // (ra+16)&7 == ra&7
                bfrag8 af0 = *(const bfrag8*)(Alds + ra * 128 + pa);
                bfrag8 af1 = *(const bfrag8*)(Alds + (ra + 16) * 128 + pa);
                #pragma unroll
                for (int nt = 0; nt < 4; ++nt) {
                    int nn = nw + nt * 16 + c;
                    bfrag8 bfv = *(const bfrag8*)(Blds + nn * 128 + ((kc ^ (nn & 7)) << 3));
                    acc[0][nt] = __builtin_amdgcn_mfma_f32_16x16x32_bf16(af0, bfv, acc[0][nt], 0, 0, 0);
                    acc[1][nt] = __builtin_amdgcn_mfma_f32_16x16x32_bf16(af1, bfv, acc[1][nt], 0, 0, 0);
                }
            }
            __syncthreads();
        }

        // ---- register-resident cell update; h stored write-through sc1 ----
        #pragma unroll
        for (int u = 0; u < 8; ++u) {
            int mt = u >> 2, reg = u & 3;
            float ig = sigm(acc[mt][0][reg] + bi_);
            float fg = sigm(acc[mt][1][reg] + bf_);
            float gv = tanh_f(acc[mt][2][reg] + bg_);
            float og = sigm(acc[mt][3][reg] + bo_);
            float cv = fg * cellv[u] + ig * gv;
            cellv[u] = cv;
            float h = og * tanh_f(cv);
            store_short_coh((unsigned short*)Hout + houti[u], bfr16(h));
            if (job && sl[u] == t) P.hidden[hidi[u]] = h;
        }

        // ---- publish: drain own stores (incl. asm ones), barrier, flag ----
        __builtin_amdgcn_s_waitcnt(0);
        __syncthreads();
        if (tid == 0)
            __hip_atomic_fetch_add(cme, 1, __ATOMIC_RELAXED, __HIP_MEMORY_SCOPE_AGENT);
    }
}

// ---------------------------------------------------------------------------
// out[b][l] = relu(hidden[b]·Wd[:,l] + bd[l]), 512 blocks x 1 wave
// ---------------------------------------------------------------------------
__global__ void k_final(const float* __restrict__ hidden, const float* __restrict__ Wd,
                        const float* __restrict__ bd, float* __restrict__ out)
{
    int b = blockIdx.x;
    int l = threadIdx.x;
    float p0 = 0.f, p1 = 0.f, p2 = 0.f;
    for (int jj = l; jj < H; jj += 64) {
        float hv = hidden[(size_t)b * H + jj];
        p0 += hv * Wd[jj * 3 + 0];
        p1 += hv * Wd[jj * 3 + 1];
        p2 += hv * Wd[jj * 3 + 2];
    }
    #pragma unroll
    for (int off = 32; off > 0; off >>= 1) {
        p0 += __shfl_down(p0, off);
        p1 += __shfl_down(p1, off);
        p2 += __shfl_down(p2, off);
    }
    if (l == 0) {
        out[b * 3 + 0] = fmaxf(p0 + bd[0], 0.f);
        out[b * 3 + 1] = fmaxf(p1 + bd[1], 0.f);
        out[b * 3 + 2] = fmaxf(p2 + bd[2], 0.f);
    }
}

extern "C" void kernel_launch(void* const* d_in, const int* in_sizes, int n_in,
                              void* d_out, int out_size, void* d_ws, size_t ws_size,
                              hipStream_t stream)
{
    const float* chars = (const float*)d_in[0];
    const int* seqlen  = (const int*)d_in[1];
    const float* W1 = (const float*)d_in[2];
    const float* U1 = (const float*)d_in[3];
    const float* b1 = (const float*)d_in[4];
    const float* W2 = (const float*)d_in[5];
    const float* U2 = (const float*)d_in[6];
    const float* b2 = (const float*)d_in[7];
    const float* Wd = (const float*)d_in[8];
    const float* bd = (const float*)d_in[9];
    float* out = (float*)d_out;

    char* ws = (char*)d_ws;
    size_t off = 0;
    bf16* Bp1 = (bf16*)(ws + off); off += (size_t)10 * NG * 128 * 2;  // 10.0 MB
    bf16* Bp2 = (bf16*)(ws + off); off += (size_t)16 * NG * 128 * 2;  // 16.0 MB
    bf16* h1  = (bf16*)(ws + off); off += (size_t)2 * BATCH * H * 2;  // 2 MB ping-pong
    bf16* h2  = (bf16*)(ws + off); off += (size_t)2 * BATCH * H * 2;  // 2 MB
    float* hidden = (float*)(ws + off); off += (size_t)BATCH * H * 4; // 2 MB
    int* cnt1 = (int*)(ws + off); off += 8 * 16 * 4;                  // 512 B
    int* cnt2 = (int*)(ws + off); off += 8 * 16 * 4;                  // 512 B
    if (ws_size < off) return;  // ~32 MB needed

    hipMemsetAsync(h1, 0, (size_t)2 * BATCH * H * 2, stream);
    hipMemsetAsync(h2, 0, (size_t)2 * BATCH * H * 2, stream);
    hipMemsetAsync(cnt1, 0, 2 * 8 * 16 * 4, stream);

    k_repack<<<dim3(10, 64), 64, 0, stream>>>(W1, U1, Bp1, 256);
    k_repack<<<dim3(16, 64), 64, 0, stream>>>(W2, U2, Bp2, 1024);

    PP P;
    P.chars = chars; P.seqlen = seqlen;
    P.Bp1 = Bp1; P.Bp2 = Bp2; P.b1 = b1; P.b2 = b2;
    P.h1 = h1; P.h2 = h2; P.hidden = hidden;
    P.cnt1 = cnt1; P.cnt2 = cnt2;

    k_persist<<<512, 256, 0, stream>>>(P);
    k_final<<<512, 64, 0, stream>>>(hidden, Wd, bd, out);
}